// Round 13
// baseline (71.917 us; speedup 1.0000x reference)
//
#include <hip/hip_runtime.h>
#include <hip/hip_fp16.h>

// Problem constants
#define NB   8
#define NC   256
#define HW   56
#define NPX  3136          // 56*56
#define RED  64
#define NG   16
#define GC   16
#define KS   7
#define KK   49
#define PADK 3
#define XPH  62            // padded rows: 3 + 56 + 3
#define XPW  64            // padded row stride (elements)
#define XPSLICE (XPH * XPW)   // 3968 f16 per channel slice
#define XT_RS 72           // xtap row stride (f16): 144 B
#define XT_CS 584          // xtap ch stride (f16)
#define WSTR  68           // wls px stride (f16)

typedef float f32x4 __attribute__((ext_vector_type(4)));
typedef _Float16 h16x4 __attribute__((ext_vector_type(4)));
typedef _Float16 h16x8 __attribute__((ext_vector_type(8)));

// ---------------------------------------------------------------------------
// K0 prep (fused), grid 665:
//  blocks 0..391  : (b = bid&7, 64-px tile): x -> xpad interior (f16) AND
//                   LDS-transpose -> xT[b][px][c] (f16)
//  blocks 392..407: w2 -> w2h [g][64m][64k] f16 (rows 49..63 zero)
//  block  408     : w1 -> w1h [64o][256c] f16
//  blocks 409..664: xpad border zeros (8 (b,c)-slices each)
// ---------------------------------------------------------------------------
__global__ __launch_bounds__(256) void prep_kernel(
    const float* __restrict__ x, const float* __restrict__ w1,
    const float* __restrict__ w2, _Float16* __restrict__ xpad,
    _Float16* __restrict__ xT, _Float16* __restrict__ w1h,
    _Float16* __restrict__ w2h) {
    int bid = blockIdx.x;
    if (bid < 392) {
        __shared__ _Float16 tls[64][65];
        int b = bid & 7, tile = bid >> 3;
        int px0 = tile * 64;
        int lane = threadIdx.x & 63;
        int cq = threadIdx.x >> 6;             // 0..3
        int px = px0 + lane;
        int h = px / HW, w = px % HW;
        const float* xb = x + (size_t)b * NC * NPX;
#pragma unroll 1
        for (int pass = 0; pass < 4; ++pass) {
#pragma unroll
            for (int rd = 0; rd < 16; ++rd) {
                int c = pass * 64 + rd * 4 + cq;
                _Float16 hv = (_Float16)xb[(size_t)c * NPX + px];
                xpad[((size_t)b * NC + c) * XPSLICE + (h + PADK) * XPW + (w + PADK)] = hv;
                tls[rd * 4 + cq][lane] = hv;
            }
            __syncthreads();
#pragma unroll
            for (int rd = 0; rd < 16; ++rd) {
                int pxw = rd * 4 + cq;
                xT[((size_t)b * NPX + px0 + pxw) * NC + pass * 64 + lane] =
                    tls[lane][pxw];
            }
            __syncthreads();
        }
    } else if (bid < 408) {
        int g = bid - 392;
#pragma unroll 4
        for (int e = threadIdx.x; e < 4096; e += 256) {
            int m = e >> 6, k = e & 63;
            float v = (m < KK) ? w2[((size_t)g * KK + m) * RED + k] : 0.0f;
            w2h[(size_t)g * 4096 + e] = (_Float16)v;
        }
    } else if (bid == 408) {
#pragma unroll 4
        for (int e = threadIdx.x; e < 64 * 256; e += 256)
            w1h[e] = (_Float16)w1[e];
    } else {
        int blk = bid - 409;                   // 0..255
        int b = blk & 7;
        int c0 = (blk >> 3) * 8;               // 8 channel slices
#pragma unroll 1
        for (int si = 0; si < 8; ++si) {
            _Float16* xd = xpad + ((size_t)b * NC + c0 + si) * XPSLICE;
            for (int e = threadIdx.x; e < 832; e += 256) {
                int row, col;
                if (e < 192)      { row = e >> 6;              col = e & 63; }
                else if (e < 384) { int f = e - 192; row = 59 + (f >> 6); col = f & 63; }
                else              { int f = e - 384; row = 3 + (f >> 3);
                                    int c8 = f & 7;  col = (c8 < 3) ? c8 : 56 + c8; }
                xd[row * XPW + col] = (_Float16)0.0f;
            }
        }
    }
}

// ---------------------------------------------------------------------------
// K1: conv1 via MFMA f16, M-split across waves. Grid 1568 (b = wgid&7) x 256.
// Wave wv computes m-tile wv: C[16 o][16 px] via 8 k-steps of 16x16x32_f16.
// A = w1h rows (b128, L1-hot), B = xT[px][c] (contiguous b128!).
// Epilogue: bn1+relu, pack 4 f16 -> tT[b][px][o].
// ---------------------------------------------------------------------------
__global__ __launch_bounds__(256) void conv1_kernel(
    const _Float16* __restrict__ xT, const _Float16* __restrict__ w1h,
    const float* __restrict__ g1, const float* __restrict__ be1,
    const float* __restrict__ mu1, const float* __restrict__ var1,
    _Float16* __restrict__ tT) {
    int lane = threadIdx.x & 63;
    int wv   = __builtin_amdgcn_readfirstlane(threadIdx.x >> 6);  // m-tile 0..3
    int wgid = blockIdx.x;                 // 1568 = 8b * 196nt
    int b  = wgid & 7;                     // XCD-aligned batch
    int nt = wgid >> 3;                    // 0..195
    int l15 = lane & 15, l4 = lane >> 4;
    int px = nt * 16 + l15;

    const _Float16* bp = xT + ((size_t)b * NPX + px) * NC + l4 * 8;
    const _Float16* ap = w1h + (wv * 16 + l15) * NC + l4 * 8;

    f32x4 acc = {0, 0, 0, 0};
#pragma unroll
    for (int kk = 0; kk < 8; ++kk) {
        h16x8 bfr = *(const h16x8*)(bp + kk * 32);
        h16x8 a   = *(const h16x8*)(ap + kk * 32);
        acc = __builtin_amdgcn_mfma_f32_16x16x32_f16(a, bfr, acc, 0, 0, 0);
    }

    // epilogue: o = wv*16 + l4*4 + r, px = nt*16 + l15
    int o0 = wv * 16 + l4 * 4;
    h16x4 pk;
#pragma unroll
    for (int r = 0; r < 4; ++r) {
        int o = o0 + r;
        float inv = g1[o] * rsqrtf(var1[o] + 1e-5f);
        float v = acc[r] * inv + (be1[o] - mu1[o] * inv);
        pk[r] = (_Float16)fmaxf(v, 0.0f);
    }
    *(h16x4*)(tT + ((size_t)b * NPX + px) * RED + o0) = pk;
}

// ---------------------------------------------------------------------------
// K2: fused conv2(MFMA f16) -> involution -> bn2 -> relu.  ONE group/block.
// Grid 6272 (XCD-swizzled 8x784), 256 thr (4 waves). LDS f16 25.4 KB.
// launch_bounds(256,6): 6 blocks/CU (LDS 153.6/160 KB), VGPR cap 85 >= 40.
// ---------------------------------------------------------------------------
__global__ __launch_bounds__(256, 6) void involution_kernel(
    const _Float16* __restrict__ xpad, const _Float16* __restrict__ tT,
    const _Float16* __restrict__ w2h, const float* __restrict__ b2,
    const float* __restrict__ g2, const float* __restrict__ be2,
    const float* __restrict__ mu2, const float* __restrict__ var2,
    float* __restrict__ out) {
    __shared__ __align__(16) _Float16 xtap[GC * XT_CS];  // 18,688 B
    __shared__ __align__(16) _Float16 wls[KK * WSTR];    //  6,664 B

    int tid  = threadIdx.x;
    int lane = tid & 63;
    int wv   = __builtin_amdgcn_readfirstlane(tid >> 6);   // 0..3 SGPR
    int wgid = blockIdx.x;
    int swz  = (wgid & 7) * 784 + (wgid >> 3);
    int tile = swz % 49;
    int g    = (swz / 49) & 15;
    int b    = swz / 784;
    int px0 = tile * 64;
    int h0  = px0 / HW;

    const _Float16* xpg = xpad + ((size_t)b * NC + (size_t)g * GC) * XPSLICE;

    // ---- step 1: issue xtap global loads (held in regs across phase A) ----
    h16x8 xr[4];
#pragma unroll
    for (int u = 0; u < 4; ++u) {
        int cid = u * 256 + tid;               // 0..1023 16B-chunks
        int ch  = cid >> 6;
        int rem = cid & 63;
        int rr  = rem >> 3, c8 = rem & 7;
        xr[u] = *(const h16x8*)(xpg + (size_t)ch * XPSLICE + (h0 + rr) * XPW + c8 * 8);
    }

    // ---- step 2: phase A MFMA  wgt[49x64px] = w2h[49x64r] . tT[64px][64r] ----
    {
        int l15 = lane & 15, l4 = lane >> 4;
        int pxc = px0 + wv * 16 + l15;
        const _Float16* tp = tT + ((size_t)b * NPX + pxc) * RED + l4 * 8;
        h16x8 bfr0 = *(const h16x8*)tp;
        h16x8 bfr1 = *(const h16x8*)(tp + 32);

        const _Float16* wA = w2h + (size_t)g * 4096;
        const float* bg = b2 + (size_t)g * KK;
        f32x4 acc0 = {0,0,0,0}, acc1 = {0,0,0,0}, acc2 = {0,0,0,0}, acc3 = {0,0,0,0};
#pragma unroll
        for (int mt = 0; mt < 4; ++mt) {
            const _Float16* ap = wA + (mt * 16 + l15) * 64 + l4 * 8;
            h16x8 a0 = *(const h16x8*)(ap);
            h16x8 a1 = *(const h16x8*)(ap + 32);
            f32x4 a = (mt == 0) ? acc0 : (mt == 1) ? acc1 : (mt == 2) ? acc2 : acc3;
            a = __builtin_amdgcn_mfma_f32_16x16x32_f16(a0, bfr0, a, 0, 0, 0);
            a = __builtin_amdgcn_mfma_f32_16x16x32_f16(a1, bfr1, a, 0, 0, 0);
            if (mt == 0) acc0 = a; else if (mt == 1) acc1 = a;
            else if (mt == 2) acc2 = a; else acc3 = a;
        }
        _Float16* wl = wls + wv * 16 + l15;
#pragma unroll
        for (int mt = 0; mt < 4; ++mt) {
            f32x4 a = (mt == 0) ? acc0 : (mt == 1) ? acc1 : (mt == 2) ? acc2 : acc3;
#pragma unroll
            for (int r = 0; r < 4; ++r) {
                int k = mt * 16 + l4 * 4 + r;
                if (k < KK) wl[k * WSTR] = (_Float16)(a[r] + bg[k]);
            }
        }
    }

    // ---- step 3: write xtap regs to LDS (16B-aligned), one barrier ----
#pragma unroll
    for (int u = 0; u < 4; ++u) {
        int cid = u * 256 + tid;
        int ch  = cid >> 6;
        int rem = cid & 63;
        int rr  = rem >> 3, c8 = rem & 7;
        *(h16x8*)&xtap[ch * XT_CS + rr * XT_RS + c8 * 8] = xr[u];
    }
    __syncthreads();

    // ---- step 4: phase B, lane = (ch, 4-px quad), f16 LDS + fma_mix ----
    int quad = tid & 15;                       // 0..15
    int ch   = tid >> 4;                       // 0..15
    int pxl  = quad * 4;
    int px_a = px0 + pxl;
    int lh   = px_a / HW - h0;                 // 0 or 1
    int w0   = px_a % HW;                      // multiple of 4

    const _Float16* xr0 = xtap + ch * XT_CS + lh * XT_RS + w0;
    float acc0 = 0.f, acc1 = 0.f, acc2 = 0.f, acc3 = 0.f;
#pragma unroll
    for (int i = 0; i < KS; ++i) {
        h16x4 t0 = *(const h16x4*)(xr0 + i * XT_RS);
        h16x4 t1 = *(const h16x4*)(xr0 + i * XT_RS + 4);
        h16x4 t2 = *(const h16x4*)(xr0 + i * XT_RS + 8);
        float cc[12];
        cc[0] = (float)t0[0]; cc[1]  = (float)t0[1]; cc[2]  = (float)t0[2]; cc[3]  = (float)t0[3];
        cc[4] = (float)t1[0]; cc[5]  = (float)t1[1]; cc[6]  = (float)t1[2]; cc[7]  = (float)t1[3];
        cc[8] = (float)t2[0]; cc[9]  = (float)t2[1]; cc[10] = (float)t2[2]; cc[11] = (float)t2[3];
#pragma unroll
        for (int j = 0; j < KS; ++j) {
            h16x4 wp = *(const h16x4*)&wls[(i * KS + j) * WSTR + pxl];
            acc0 = fmaf((float)wp[0], cc[j + 0], acc0);
            acc1 = fmaf((float)wp[1], cc[j + 1], acc1);
            acc2 = fmaf((float)wp[2], cc[j + 2], acc2);
            acc3 = fmaf((float)wp[3], cc[j + 3], acc3);
        }
    }

    int c_ = g * GC + ch;
    float inv = g2[c_] * rsqrtf(var2[c_] + 1e-5f);
    float off = be2[c_] - mu2[c_] * inv;
    f32x4 o;
    o[0] = fmaxf(acc0 * inv + off, 0.0f);
    o[1] = fmaxf(acc1 * inv + off, 0.0f);
    o[2] = fmaxf(acc2 * inv + off, 0.0f);
    o[3] = fmaxf(acc3 * inv + off, 0.0f);
    *(f32x4*)(out + ((size_t)b * NC + c_) * NPX + px_a) = o;
}

// ---------------------------------------------------------------------------
extern "C" void kernel_launch(void* const* d_in, const int* in_sizes, int n_in,
                              void* d_out, int out_size, void* d_ws, size_t ws_size,
                              hipStream_t stream) {
    const float* x    = (const float*)d_in[0];
    const float* w1   = (const float*)d_in[1];
    const float* g1   = (const float*)d_in[2];
    const float* be1  = (const float*)d_in[3];
    const float* mu1  = (const float*)d_in[4];
    const float* var1 = (const float*)d_in[5];
    const float* w2   = (const float*)d_in[6];
    const float* b2   = (const float*)d_in[7];
    const float* g2   = (const float*)d_in[8];
    const float* be2  = (const float*)d_in[9];
    const float* mu2  = (const float*)d_in[10];
    const float* var2 = (const float*)d_in[11];
    float* outp = (float*)d_out;

    // ws: xpad f16 16.3MB | xT f16 12.8MB | tT f16 3.2MB | w2h 128KB | w1h 32KB
    _Float16* xpad = (_Float16*)d_ws;
    _Float16* xT   = xpad + (size_t)NB * NC * XPSLICE;
    _Float16* tT   = xT + (size_t)NB * NPX * NC;
    _Float16* w2h  = tT + (size_t)NB * NPX * RED;
    _Float16* w1h  = w2h + (size_t)NG * 4096;

    prep_kernel<<<665, 256, 0, stream>>>(x, w1, w2, xpad, xT, w1h, w2h);
    conv1_kernel<<<1568, 256, 0, stream>>>(xT, w1h, g1, be1, mu1, var1, tT);
    involution_kernel<<<6272, 256, 0, stream>>>(
        xpad, tT, w2h, b2, g2, be2, mu2, var2, outp);
}

// Round 14
// 67.411 us; speedup vs baseline: 1.0668x; 1.0668x over previous
//
#include <hip/hip_runtime.h>
#include <hip/hip_fp16.h>

// Problem constants
#define NB   8
#define NC   256
#define HW   56
#define NPX  3136          // 56*56
#define RED  64
#define NG   16
#define GC   16
#define KS   7
#define KK   49
#define PADK 3
#define XPH  62            // padded rows: 3 + 56 + 3
#define XPW  64            // padded row stride (elements)
#define XPSLICE (XPH * XPW)   // 3968 f16 per channel slice
#define XT_RS 72           // xtap row stride (f16): 144 B
#define XT_CS 584          // xtap ch stride (f16)
#define WSTR  68           // wls px stride (f16)

typedef float f32x4 __attribute__((ext_vector_type(4)));
typedef _Float16 h16x4 __attribute__((ext_vector_type(4)));
typedef _Float16 h16x8 __attribute__((ext_vector_type(8)));

// ---------------------------------------------------------------------------
// K0: fused prep (r12 version).  blocks 0..2047: pad+convert x -> xpad f16
//     (incl. border); blocks 2048..2063: w2 -> w2h f16; block 2064: w1 -> w1h.
// ---------------------------------------------------------------------------
__global__ __launch_bounds__(256) void prep_kernel(
    const float* __restrict__ x, const float* __restrict__ w1,
    const float* __restrict__ w2, _Float16* __restrict__ xpad,
    _Float16* __restrict__ w1h, _Float16* __restrict__ w2h) {
    int bid = blockIdx.x;
    if (bid < NB * NC) {
        const float* xs = x + (size_t)bid * NPX;
        _Float16* xd = xpad + (size_t)bid * XPSLICE;
#pragma unroll 4
        for (int e = threadIdx.x; e < XPSLICE; e += 256) {
            int row = e >> 6, col = e & 63;
            int h = row - PADK, w = col - PADK;
            float v = (h >= 0 && h < HW && w >= 0 && w < HW) ? xs[h * HW + w] : 0.0f;
            xd[e] = (_Float16)v;
        }
    } else if (bid < NB * NC + NG) {
        int g = bid - NB * NC;
#pragma unroll 4
        for (int e = threadIdx.x; e < 4096; e += 256) {
            int m = e >> 6, k = e & 63;
            float v = (m < KK) ? w2[((size_t)g * KK + m) * RED + k] : 0.0f;
            w2h[(size_t)g * 4096 + e] = (_Float16)v;
        }
    } else {
#pragma unroll 4
        for (int e = threadIdx.x; e < 64 * 256; e += 256)
            w1h[e] = (_Float16)w1[e];
    }
}

// ---------------------------------------------------------------------------
// K1: conv1 via MFMA f16, M-SPLIT across 4 waves (occupancy fix vs r12).
// Grid 1568 (8b x 196 nt; b = wgid&7 -> XCD-local batch) x 256 thr (4 waves).
// Wave wv owns m-tile wv: C[16 o][16 px], 8 k-steps of mfma_16x16x32_f16.
// B-frags: 8 channel-strided u16 gathers per k-step from xpad (shared across
// the 4 waves -> L1 hits for 3 of 4). A = w1h rows (b128, L1-hot).
// 6272 waves total = 6.1/SIMD. Epilogue: bn1+relu -> f16 -> tT[b][px][o].
// ---------------------------------------------------------------------------
__global__ __launch_bounds__(256) void conv1_kernel(
    const _Float16* __restrict__ xpad, const _Float16* __restrict__ w1h,
    const float* __restrict__ g1, const float* __restrict__ be1,
    const float* __restrict__ mu1, const float* __restrict__ var1,
    _Float16* __restrict__ tT) {
    int lane = threadIdx.x & 63;
    int wv   = __builtin_amdgcn_readfirstlane(threadIdx.x >> 6);  // m-tile 0..3
    int wgid = blockIdx.x;                 // 1568 = 8b * 196nt
    int b  = wgid & 7;                     // XCD-aligned batch
    int nt = wgid >> 3;                    // 0..195
    int l15 = lane & 15, l4 = lane >> 4;
    int px = nt * 16 + l15;
    int h = px / HW, w = px % HW;

    const _Float16* xp = xpad + (size_t)b * NC * XPSLICE
                       + (h + PADK) * XPW + (w + PADK);
    const _Float16* ap0 = w1h + (wv * 16 + l15) * NC + l4 * 8;

    f32x4 acc = {0, 0, 0, 0};
#pragma unroll
    for (int kk = 0; kk < 8; ++kk) {
        h16x8 bfr;
#pragma unroll
        for (int i = 0; i < 8; ++i)
            bfr[i] = xp[(size_t)(kk * 32 + l4 * 8 + i) * XPSLICE];
        h16x8 a = *(const h16x8*)(ap0 + kk * 32);
        acc = __builtin_amdgcn_mfma_f32_16x16x32_f16(a, bfr, acc, 0, 0, 0);
    }

    // epilogue: o = wv*16 + l4*4 + r, px = nt*16 + l15
    int o0 = wv * 16 + l4 * 4;
    h16x4 pk;
#pragma unroll
    for (int r = 0; r < 4; ++r) {
        int o = o0 + r;
        float inv = g1[o] * rsqrtf(var1[o] + 1e-5f);
        float v = acc[r] * inv + (be1[o] - mu1[o] * inv);
        pk[r] = (_Float16)fmaxf(v, 0.0f);
    }
    *(h16x4*)(tT + ((size_t)b * NPX + px) * RED + o0) = pk;
}

// ---------------------------------------------------------------------------
// K2: fused conv2(MFMA f16) -> involution -> bn2 -> relu (r12 verbatim).
// Grid 6272 (XCD-swizzled 8x784), 256 thr (4 waves). LDS f16 25.4 KB.
// ---------------------------------------------------------------------------
__global__ __launch_bounds__(256, 6) void involution_kernel(
    const _Float16* __restrict__ xpad, const _Float16* __restrict__ tT,
    const _Float16* __restrict__ w2h, const float* __restrict__ b2,
    const float* __restrict__ g2, const float* __restrict__ be2,
    const float* __restrict__ mu2, const float* __restrict__ var2,
    float* __restrict__ out) {
    __shared__ __align__(16) _Float16 xtap[GC * XT_CS];  // 18,688 B
    __shared__ __align__(16) _Float16 wls[KK * WSTR];    //  6,664 B

    int tid  = threadIdx.x;
    int lane = tid & 63;
    int wv   = __builtin_amdgcn_readfirstlane(tid >> 6);   // 0..3 SGPR
    int wgid = blockIdx.x;
    int swz  = (wgid & 7) * 784 + (wgid >> 3);
    int tile = swz % 49;
    int g    = (swz / 49) & 15;
    int b    = swz / 784;
    int px0 = tile * 64;
    int h0  = px0 / HW;

    const _Float16* xpg = xpad + ((size_t)b * NC + (size_t)g * GC) * XPSLICE;

    // ---- step 1: issue xtap global loads (held in regs across phase A) ----
    h16x8 xr[4];
#pragma unroll
    for (int u = 0; u < 4; ++u) {
        int cid = u * 256 + tid;               // 0..1023 16B-chunks
        int ch  = cid >> 6;
        int rem = cid & 63;
        int rr  = rem >> 3, c8 = rem & 7;
        xr[u] = *(const h16x8*)(xpg + (size_t)ch * XPSLICE + (h0 + rr) * XPW + c8 * 8);
    }

    // ---- step 2: phase A MFMA  wgt[49x64px] = w2h[49x64r] . tT[64px][64r] ----
    {
        int l15 = lane & 15, l4 = lane >> 4;
        int pxc = px0 + wv * 16 + l15;
        const _Float16* tp = tT + ((size_t)b * NPX + pxc) * RED + l4 * 8;
        h16x8 bfr0 = *(const h16x8*)tp;
        h16x8 bfr1 = *(const h16x8*)(tp + 32);

        const _Float16* wA = w2h + (size_t)g * 4096;
        const float* bg = b2 + (size_t)g * KK;
        f32x4 acc0 = {0,0,0,0}, acc1 = {0,0,0,0}, acc2 = {0,0,0,0}, acc3 = {0,0,0,0};
#pragma unroll
        for (int mt = 0; mt < 4; ++mt) {
            const _Float16* ap = wA + (mt * 16 + l15) * 64 + l4 * 8;
            h16x8 a0 = *(const h16x8*)(ap);
            h16x8 a1 = *(const h16x8*)(ap + 32);
            f32x4 a = (mt == 0) ? acc0 : (mt == 1) ? acc1 : (mt == 2) ? acc2 : acc3;
            a = __builtin_amdgcn_mfma_f32_16x16x32_f16(a0, bfr0, a, 0, 0, 0);
            a = __builtin_amdgcn_mfma_f32_16x16x32_f16(a1, bfr1, a, 0, 0, 0);
            if (mt == 0) acc0 = a; else if (mt == 1) acc1 = a;
            else if (mt == 2) acc2 = a; else acc3 = a;
        }
        _Float16* wl = wls + wv * 16 + l15;
#pragma unroll
        for (int mt = 0; mt < 4; ++mt) {
            f32x4 a = (mt == 0) ? acc0 : (mt == 1) ? acc1 : (mt == 2) ? acc2 : acc3;
#pragma unroll
            for (int r = 0; r < 4; ++r) {
                int k = mt * 16 + l4 * 4 + r;
                if (k < KK) wl[k * WSTR] = (_Float16)(a[r] + bg[k]);
            }
        }
    }

    // ---- step 3: write xtap regs to LDS (16B-aligned), one barrier ----
#pragma unroll
    for (int u = 0; u < 4; ++u) {
        int cid = u * 256 + tid;
        int ch  = cid >> 6;
        int rem = cid & 63;
        int rr  = rem >> 3, c8 = rem & 7;
        *(h16x8*)&xtap[ch * XT_CS + rr * XT_RS + c8 * 8] = xr[u];
    }
    __syncthreads();

    // ---- step 4: phase B, lane = (ch, 4-px quad), f16 LDS + fma_mix ----
    int quad = tid & 15;                       // 0..15
    int ch   = tid >> 4;                       // 0..15
    int pxl  = quad * 4;
    int px_a = px0 + pxl;
    int lh   = px_a / HW - h0;                 // 0 or 1
    int w0   = px_a % HW;                      // multiple of 4

    const _Float16* xr0 = xtap + ch * XT_CS + lh * XT_RS + w0;
    float acc0 = 0.f, acc1 = 0.f, acc2 = 0.f, acc3 = 0.f;
#pragma unroll
    for (int i = 0; i < KS; ++i) {
        h16x4 t0 = *(const h16x4*)(xr0 + i * XT_RS);
        h16x4 t1 = *(const h16x4*)(xr0 + i * XT_RS + 4);
        h16x4 t2 = *(const h16x4*)(xr0 + i * XT_RS + 8);
        float cc[12];
        cc[0] = (float)t0[0]; cc[1]  = (float)t0[1]; cc[2]  = (float)t0[2]; cc[3]  = (float)t0[3];
        cc[4] = (float)t1[0]; cc[5]  = (float)t1[1]; cc[6]  = (float)t1[2]; cc[7]  = (float)t1[3];
        cc[8] = (float)t2[0]; cc[9]  = (float)t2[1]; cc[10] = (float)t2[2]; cc[11] = (float)t2[3];
#pragma unroll
        for (int j = 0; j < KS; ++j) {
            h16x4 wp = *(const h16x4*)&wls[(i * KS + j) * WSTR + pxl];
            acc0 = fmaf((float)wp[0], cc[j + 0], acc0);
            acc1 = fmaf((float)wp[1], cc[j + 1], acc1);
            acc2 = fmaf((float)wp[2], cc[j + 2], acc2);
            acc3 = fmaf((float)wp[3], cc[j + 3], acc3);
        }
    }

    int c_ = g * GC + ch;
    float inv = g2[c_] * rsqrtf(var2[c_] + 1e-5f);
    float off = be2[c_] - mu2[c_] * inv;
    f32x4 o;
    o[0] = fmaxf(acc0 * inv + off, 0.0f);
    o[1] = fmaxf(acc1 * inv + off, 0.0f);
    o[2] = fmaxf(acc2 * inv + off, 0.0f);
    o[3] = fmaxf(acc3 * inv + off, 0.0f);
    *(f32x4*)(out + ((size_t)b * NC + c_) * NPX + px_a) = o;
}

// ---------------------------------------------------------------------------
extern "C" void kernel_launch(void* const* d_in, const int* in_sizes, int n_in,
                              void* d_out, int out_size, void* d_ws, size_t ws_size,
                              hipStream_t stream) {
    const float* x    = (const float*)d_in[0];
    const float* w1   = (const float*)d_in[1];
    const float* g1   = (const float*)d_in[2];
    const float* be1  = (const float*)d_in[3];
    const float* mu1  = (const float*)d_in[4];
    const float* var1 = (const float*)d_in[5];
    const float* w2   = (const float*)d_in[6];
    const float* b2   = (const float*)d_in[7];
    const float* g2   = (const float*)d_in[8];
    const float* be2  = (const float*)d_in[9];
    const float* mu2  = (const float*)d_in[10];
    const float* var2 = (const float*)d_in[11];
    float* outp = (float*)d_out;

    // ws: xpad f16 16.3MB | tT f16 3.2MB | w2h 128KB | w1h 32KB
    _Float16* xpad = (_Float16*)d_ws;
    _Float16* tT   = xpad + (size_t)NB * NC * XPSLICE;
    _Float16* w2h  = tT + (size_t)NB * NPX * RED;
    _Float16* w1h  = w2h + (size_t)NG * 4096;

    prep_kernel<<<NB * NC + NG + 1, 256, 0, stream>>>(x, w1, w2, xpad, w1h, w2h);
    conv1_kernel<<<1568, 256, 0, stream>>>(xpad, w1h, g1, be1, mu1, var1, tT);
    involution_kernel<<<6272, 256, 0, stream>>>(
        xpad, tT, w2h, b2, g2, be2, mu2, var2, outp);
}

// Round 15
// 64.144 us; speedup vs baseline: 1.1212x; 1.0509x over previous
//
#include <hip/hip_runtime.h>
#include <hip/hip_fp16.h>

// Problem constants
#define NB   8
#define NC   256
#define HW   56
#define NPX  3136          // 56*56
#define RED  64
#define NG   16
#define GC   16
#define KS   7
#define KK   49
#define PADK 3
#define XPH  62            // padded rows: 3 + 56 + 3
#define XPW  64            // padded row stride (elements)
#define XPSLICE (XPH * XPW)   // 3968 f16 per channel slice
// K2 tiling
#define TPX  224           // px tile = 4 full pixel rows
#define NT2  14            // 3136 / 224
#define XT2_CS 644         // xtap ch stride (f16): 10*64+4 -> bank spread
#define WSTR2  232         // wls px stride (f16): 464 B, 16B-multiple

typedef float f32x4 __attribute__((ext_vector_type(4)));
typedef _Float16 h16x4 __attribute__((ext_vector_type(4)));
typedef _Float16 h16x8 __attribute__((ext_vector_type(8)));

// ---------------------------------------------------------------------------
// K0: fused prep (r12 version).  blocks 0..2047: pad+convert x -> xpad f16
//     (incl. border); blocks 2048..2063: w2 -> w2h f16; block 2064: w1 -> w1h.
// ---------------------------------------------------------------------------
__global__ __launch_bounds__(256) void prep_kernel(
    const float* __restrict__ x, const float* __restrict__ w1,
    const float* __restrict__ w2, _Float16* __restrict__ xpad,
    _Float16* __restrict__ w1h, _Float16* __restrict__ w2h) {
    int bid = blockIdx.x;
    if (bid < NB * NC) {
        const float* xs = x + (size_t)bid * NPX;
        _Float16* xd = xpad + (size_t)bid * XPSLICE;
#pragma unroll 4
        for (int e = threadIdx.x; e < XPSLICE; e += 256) {
            int row = e >> 6, col = e & 63;
            int h = row - PADK, w = col - PADK;
            float v = (h >= 0 && h < HW && w >= 0 && w < HW) ? xs[h * HW + w] : 0.0f;
            xd[e] = (_Float16)v;
        }
    } else if (bid < NB * NC + NG) {
        int g = bid - NB * NC;
#pragma unroll 4
        for (int e = threadIdx.x; e < 4096; e += 256) {
            int m = e >> 6, k = e & 63;
            float v = (m < KK) ? w2[((size_t)g * KK + m) * RED + k] : 0.0f;
            w2h[(size_t)g * 4096 + e] = (_Float16)v;
        }
    } else {
#pragma unroll 4
        for (int e = threadIdx.x; e < 64 * 256; e += 256)
            w1h[e] = (_Float16)w1[e];
    }
}

// ---------------------------------------------------------------------------
// K1: conv1 via MFMA f16 (r12 version, 1 wave/block).
// Grid 1568 (8b x 196 nt; b = wgid&7), 64 thr. Wave computes C[64 o][16 px]:
// 8 k-steps x 4 m-tiles. B = xpad gathers (8 per k-step), A = w1h b128.
// ---------------------------------------------------------------------------
__global__ __launch_bounds__(64) void conv1_kernel(
    const _Float16* __restrict__ xpad, const _Float16* __restrict__ w1h,
    const float* __restrict__ g1, const float* __restrict__ be1,
    const float* __restrict__ mu1, const float* __restrict__ var1,
    _Float16* __restrict__ tT) {
    int lane = threadIdx.x;
    int l15 = lane & 15, l4 = lane >> 4;
    int wgid = blockIdx.x;                 // 1568 = 8 * 196
    int b  = wgid & 7;                     // XCD-local batch
    int nt = wgid >> 3;                    // 0..195
    int px = nt * 16 + l15;
    int h = px / HW, w = px % HW;

    const _Float16* xp = xpad + (size_t)b * NC * XPSLICE
                       + (h + PADK) * XPW + (w + PADK);

    f32x4 acc0 = {0,0,0,0}, acc1 = {0,0,0,0}, acc2 = {0,0,0,0}, acc3 = {0,0,0,0};
#pragma unroll
    for (int kk = 0; kk < 8; ++kk) {
        h16x8 bfr;
#pragma unroll
        for (int i = 0; i < 8; ++i)
            bfr[i] = xp[(size_t)(kk * 32 + l4 * 8 + i) * XPSLICE];
#pragma unroll
        for (int mt = 0; mt < 4; ++mt) {
            const _Float16* ap = w1h + (mt * 16 + l15) * NC + kk * 32 + l4 * 8;
            h16x8 a = *(const h16x8*)ap;
            f32x4 c = (mt == 0) ? acc0 : (mt == 1) ? acc1 : (mt == 2) ? acc2 : acc3;
            c = __builtin_amdgcn_mfma_f32_16x16x32_f16(a, bfr, c, 0, 0, 0);
            if (mt == 0) acc0 = c; else if (mt == 1) acc1 = c;
            else if (mt == 2) acc2 = c; else acc3 = c;
        }
    }

    _Float16* tb = tT + ((size_t)b * NPX + px) * RED;
#pragma unroll
    for (int mt = 0; mt < 4; ++mt) {
        f32x4 a = (mt == 0) ? acc0 : (mt == 1) ? acc1 : (mt == 2) ? acc2 : acc3;
        int o0 = mt * 16 + l4 * 4;
        h16x4 pk;
#pragma unroll
        for (int r = 0; r < 4; ++r) {
            int o = o0 + r;
            float inv = g1[o] * rsqrtf(var1[o] + 1e-5f);
            float v = a[r] * inv + (be1[o] - mu1[o] * inv);
            pk[r] = (_Float16)fmaxf(v, 0.0f);
        }
        *(h16x4*)(tb + o0) = pk;
    }
}

// ---------------------------------------------------------------------------
// K2: fused conv2(MFMA f16) -> involution -> bn2 -> relu.
// Tile = 224 px (4 full rows) x 1 group. Grid 1792 (XCD-swizzled 8x224),
// block 448 = 7 waves. LDS: xtap [16ch][10rows][64] ch-stride 644 (20.6 KB)
// + wls [49][232] (22.7 KB) = 43.3 KB -> 3 blocks/CU.
// Step 1 (T14): 3x b128 staging loads (global->reg), written after phase A.
// Step 2: phase A MFMA; 7 waves x 2 N-tiles (A-frags hoisted+reused).
// Step 3: reg->LDS, ONE barrier.
// Step 4: phase B thread = (octet,ch): 8 px x 1 ch. Per i: 2 b128 taps;
//   per (i,j): 1 b128 wq (16-way ch-broadcast: lane = octet*16+ch).
//   63 LDS reads / 392 FMA per thread. bn2+relu, 2x f32x4 stores.
// ---------------------------------------------------------------------------
__global__ __launch_bounds__(448, 3) void involution_kernel(
    const _Float16* __restrict__ xpad, const _Float16* __restrict__ tT,
    const _Float16* __restrict__ w2h, const float* __restrict__ b2,
    const float* __restrict__ g2, const float* __restrict__ be2,
    const float* __restrict__ mu2, const float* __restrict__ var2,
    float* __restrict__ out) {
    __shared__ __align__(16) _Float16 xtap[GC * XT2_CS];  // 20,608 B
    __shared__ __align__(16) _Float16 wls[KK * WSTR2];    // 22,736 B

    int tid  = threadIdx.x;
    int lane = tid & 63;
    int wv   = __builtin_amdgcn_readfirstlane(tid >> 6);   // 0..6 SGPR
    // XCD swizzle: 1792 = 8 * 224; each XCD owns one batch
    int wgid = blockIdx.x;
    int swz  = (wgid & 7) * 224 + (wgid >> 3);
    int b    = swz / 224;
    int rem  = swz % 224;
    int g    = rem / NT2;                  // 0..15
    int tile = rem % NT2;                  // 0..13
    int px0 = tile * TPX;
    int R0  = tile * 4;                    // first output pixel-row

    const _Float16* xpg = xpad + ((size_t)b * NC + (size_t)g * GC) * XPSLICE;

    // ---- step 1: issue xtap staging loads (16ch x 10rows x 64col = 1280 chunks)
    h16x8 xr[3];
#pragma unroll
    for (int u = 0; u < 3; ++u) {
        int cid = u * 448 + tid;
        if (cid < 1280) {
            int ch = cid / 80;             // 80 = 10 rows * 8 chunks
            int rm = cid % 80;
            int rr = rm >> 3, c8 = rm & 7;
            xr[u] = *(const h16x8*)(xpg + (size_t)ch * XPSLICE
                                    + (R0 + rr) * XPW + c8 * 8);
        }
    }

    // ---- step 2: phase A MFMA  wgt[49 x 224px] = w2h[49x64r] . tT[px][64r] ----
    {
        int l15 = lane & 15, l4 = lane >> 4;
        const _Float16* wA = w2h + (size_t)g * 4096;
        const float* bg = b2 + (size_t)g * KK;
        // hoist A-fragments (reused across both N-tiles)
        h16x8 a0[4], a1[4];
#pragma unroll
        for (int mt = 0; mt < 4; ++mt) {
            const _Float16* ap = wA + (mt * 16 + l15) * 64 + l4 * 8;
            a0[mt] = *(const h16x8*)(ap);
            a1[mt] = *(const h16x8*)(ap + 32);
        }
#pragma unroll
        for (int it = 0; it < 2; ++it) {
            int nt = wv * 2 + it;          // 0..13 (wave-uniform)
            int pxc = px0 + nt * 16 + l15;
            const _Float16* tp = tT + ((size_t)b * NPX + pxc) * RED + l4 * 8;
            h16x8 bfr0 = *(const h16x8*)tp;
            h16x8 bfr1 = *(const h16x8*)(tp + 32);

            f32x4 acc0 = {0,0,0,0}, acc1 = {0,0,0,0},
                  acc2 = {0,0,0,0}, acc3 = {0,0,0,0};
#pragma unroll
            for (int mt = 0; mt < 4; ++mt) {
                f32x4 a = (mt == 0) ? acc0 : (mt == 1) ? acc1
                        : (mt == 2) ? acc2 : acc3;
                a = __builtin_amdgcn_mfma_f32_16x16x32_f16(a0[mt], bfr0, a, 0, 0, 0);
                a = __builtin_amdgcn_mfma_f32_16x16x32_f16(a1[mt], bfr1, a, 0, 0, 0);
                if (mt == 0) acc0 = a; else if (mt == 1) acc1 = a;
                else if (mt == 2) acc2 = a; else acc3 = a;
            }
            _Float16* wl = wls + nt * 16 + l15;
#pragma unroll
            for (int mt = 0; mt < 4; ++mt) {
                f32x4 a = (mt == 0) ? acc0 : (mt == 1) ? acc1
                        : (mt == 2) ? acc2 : acc3;
#pragma unroll
                for (int r = 0; r < 4; ++r) {
                    int k = mt * 16 + l4 * 4 + r;
                    if (k < KK) wl[k * WSTR2] = (_Float16)(a[r] + bg[k]);
                }
            }
        }
    }

    // ---- step 3: write staged regs to LDS, ONE barrier ----
#pragma unroll
    for (int u = 0; u < 3; ++u) {
        int cid = u * 448 + tid;
        if (cid < 1280) {
            int ch = cid / 80;
            int rm = cid % 80;
            int rr = rm >> 3, c8 = rm & 7;
            *(h16x8*)&xtap[ch * XT2_CS + rr * 64 + c8 * 8] = xr[u];
        }
    }
    __syncthreads();

    // ---- step 4: phase B, thread = (octet, ch): 8 px x 1 ch ----
    int octet = tid >> 4;                  // 0..27
    int ch    = tid & 15;                  // 0..15
    int lin   = octet * 8;                 // 0..216
    int lh    = lin / 56;                  // 0..3
    int w0    = lin % 56;                  // multiple of 8

    const _Float16* xb0 = xtap + ch * XT2_CS + lh * 64 + w0;
    float acc[8];
#pragma unroll
    for (int p = 0; p < 8; ++p) acc[p] = 0.0f;

#pragma unroll
    for (int i = 0; i < KS; ++i) {
        h16x8 t0 = *(const h16x8*)(xb0 + i * 64);       // cols w0..w0+7
        h16x8 t1 = *(const h16x8*)(xb0 + i * 64 + 8);   // cols w0+8..w0+15
        float cc[16];
#pragma unroll
        for (int p = 0; p < 8; ++p) { cc[p] = (float)t0[p]; cc[8 + p] = (float)t1[p]; }
#pragma unroll
        for (int j = 0; j < KS; ++j) {
            h16x8 wq = *(const h16x8*)&wls[(i * KS + j) * WSTR2 + lin];
#pragma unroll
            for (int p = 0; p < 8; ++p)
                acc[p] = fmaf((float)wq[p], cc[j + p], acc[p]);
        }
    }

    int c_ = g * GC + ch;
    float inv = g2[c_] * rsqrtf(var2[c_] + 1e-5f);
    float off = be2[c_] - mu2[c_] * inv;
    float* op = out + ((size_t)b * NC + c_) * NPX + px0 + lin;
    f32x4 o0, o1;
#pragma unroll
    for (int p = 0; p < 4; ++p) {
        o0[p] = fmaxf(acc[p] * inv + off, 0.0f);
        o1[p] = fmaxf(acc[4 + p] * inv + off, 0.0f);
    }
    *(f32x4*)(op)     = o0;
    *(f32x4*)(op + 4) = o1;
}

// ---------------------------------------------------------------------------
extern "C" void kernel_launch(void* const* d_in, const int* in_sizes, int n_in,
                              void* d_out, int out_size, void* d_ws, size_t ws_size,
                              hipStream_t stream) {
    const float* x    = (const float*)d_in[0];
    const float* w1   = (const float*)d_in[1];
    const float* g1   = (const float*)d_in[2];
    const float* be1  = (const float*)d_in[3];
    const float* mu1  = (const float*)d_in[4];
    const float* var1 = (const float*)d_in[5];
    const float* w2   = (const float*)d_in[6];
    const float* b2   = (const float*)d_in[7];
    const float* g2   = (const float*)d_in[8];
    const float* be2  = (const float*)d_in[9];
    const float* mu2  = (const float*)d_in[10];
    const float* var2 = (const float*)d_in[11];
    float* outp = (float*)d_out;

    // ws: xpad f16 16.3MB | tT f16 3.2MB | w2h 128KB | w1h 32KB
    _Float16* xpad = (_Float16*)d_ws;
    _Float16* tT   = xpad + (size_t)NB * NC * XPSLICE;
    _Float16* w2h  = tT + (size_t)NB * NPX * RED;
    _Float16* w1h  = w2h + (size_t)NG * 4096;

    prep_kernel<<<NB * NC + NG + 1, 256, 0, stream>>>(x, w1, w2, xpad, w1h, w2h);
    conv1_kernel<<<1568, 64, 0, stream>>>(xpad, w1h, g1, be1, mu1, var1, tT);
    involution_kernel<<<1792, 448, 0, stream>>>(
        xpad, tT, w2h, b2, g2, be2, mu2, var2, outp);
}